// Round 1
// baseline (511.089 us; speedup 1.0000x reference)
//
#include <hip/hip_runtime.h>
#include <math.h>

// S4 forward, restructured as:
//   p[b,t] = u[b,t,:]·W_in          (K1, blocks 1..1024)
//   h[k]   = C·A_bar^k·B_bar        (K1, block 0: Taylor expm + squarings + chains)
//   s[b,t] = D·p[b,t] + sum_{k<t} h[k]·p[b,t-1-k]   (K2 conv, LDS-resident)
//   out[b,t,d] = s[b,t]·W_out[d]    (K2 epilogue, coalesced stream)

#define S0 (Lh)
#define S1 (Lh + 4096)
#define S2 (Lh + 8192)
#define S3 (Lh + 12288)

// C[i0+r][j0+s] += sum_l XT[l][i0+r] * Y[l][j0+s]   (i.e. C = X·Y given X^T)
// Inner reads are "whole row l" -> broadcast/2-way, conflict-free.
__device__ __forceinline__ void mm64_core(const float* XT, const float* Y,
                                          int i0, int j0, float c[4][4]) {
#pragma unroll 4
  for (int l = 0; l < 64; ++l) {
    float4 xv = *(const float4*)(XT + l * 64 + i0);
    float4 yv = *(const float4*)(Y + l * 64 + j0);
    c[0][0] += xv.x * yv.x; c[0][1] += xv.x * yv.y; c[0][2] += xv.x * yv.z; c[0][3] += xv.x * yv.w;
    c[1][0] += xv.y * yv.x; c[1][1] += xv.y * yv.y; c[1][2] += xv.y * yv.z; c[1][3] += xv.y * yv.w;
    c[2][0] += xv.z * yv.x; c[2][1] += xv.z * yv.y; c[2][2] += xv.z * yv.z; c[2][3] += xv.z * yv.w;
    c[3][0] += xv.w * yv.x; c[3][1] += xv.w * yv.y; c[3][2] += xv.w * yv.z; c[3][3] += xv.w * yv.w;
  }
}

__device__ __forceinline__ void store_tile(float* Cp, int i0, int j0, float c[4][4]) {
#pragma unroll
  for (int r = 0; r < 4; ++r)
    *(float4*)(Cp + (i0 + r) * 64 + j0) = make_float4(c[r][0], c[r][1], c[r][2], c[r][3]);
}

// 63-step matvec chain: v_{j+1}[ln] = dot(rowsrc row ln, v_j), records all 64
// vectors as rows of outT: outT[ln][j] = v_j[ln].  Single wave (lanes ln=0..63).
__device__ __forceinline__ void chain64(const float* rowsrc, volatile float* ubuf,
                                        float* outT, int ln, float v0) {
  float row[64];
#pragma unroll
  for (int q = 0; q < 16; ++q) {
    float4 rv = *(const float4*)(rowsrc + ln * 64 + 4 * q);
    row[4 * q] = rv.x; row[4 * q + 1] = rv.y; row[4 * q + 2] = rv.z; row[4 * q + 3] = rv.w;
  }
  float v = v0;
  for (int jq = 0; jq < 16; ++jq) {
    float q0, q1, q2, q3;
    q0 = v;
    // three steps inside the quad
#pragma unroll
    for (int m = 1; m < 4; ++m) {
      ubuf[ln] = v;
      float a0 = 0.f, a1 = 0.f, a2 = 0.f, a3 = 0.f;
#pragma unroll
      for (int q = 0; q < 16; ++q) {
        float u0 = ubuf[4 * q], u1 = ubuf[4 * q + 1], u2 = ubuf[4 * q + 2], u3 = ubuf[4 * q + 3];
        a0 += row[4 * q] * u0; a1 += row[4 * q + 1] * u1;
        a2 += row[4 * q + 2] * u2; a3 += row[4 * q + 3] * u3;
      }
      v = (a0 + a1) + (a2 + a3);
      if (m == 1) q1 = v; else if (m == 2) q2 = v; else q3 = v;
    }
    *(float4*)(outT + ln * 64 + 4 * jq) = make_float4(q0, q1, q2, q3);
    if (jq < 15) {  // one more step to seed next quad
      ubuf[ln] = v;
      float a0 = 0.f, a1 = 0.f, a2 = 0.f, a3 = 0.f;
#pragma unroll
      for (int q = 0; q < 16; ++q) {
        float u0 = ubuf[4 * q], u1 = ubuf[4 * q + 1], u2 = ubuf[4 * q + 2], u3 = ubuf[4 * q + 3];
        a0 += row[4 * q] * u0; a1 += row[4 * q + 1] * u1;
        a2 += row[4 * q + 2] * u2; a3 += row[4 * q + 3] * u3;
      }
      v = (a0 + a1) + (a2 + a3);
    }
  }
}

extern "C" __global__ __launch_bounds__(256) void s4_k1(
    const float* __restrict__ u, const float* __restrict__ A, const float* __restrict__ B,
    const float* __restrict__ C, const float* __restrict__ logdt, const float* __restrict__ Win,
    float* __restrict__ p_ws, float* __restrict__ h_ws) {
  __shared__ __align__(16) float Lh[16384];  // 64 KB: 4 slots of 64x64 f32
  const int tid = threadIdx.x;

  if (blockIdx.x == 0) {
    // ================= h[k] pipeline (one block) =================
    float dt = expf(logdt[0]);
    dt = fminf(fmaxf(dt, 0.001f), 0.1f);

    // load dA = dt*A into S0 (row-major) and dAT into S1
#pragma unroll
    for (int n = 0; n < 16; ++n) {
      int e = tid * 16 + n;
      int i = e >> 6, j = e & 63;
      float v = A[e] * dt;
      S0[e] = v;
      S1[j * 64 + i] = v;
    }
    __syncthreads();

    const int i0 = (tid & 15) << 2, j0 = (tid >> 4) << 2;
    const int bi = tid & 63, bq = tid >> 6;

    // A_bar tile accumulator: I + dA + sum_{k=2..8} dA^k/k!
    float ab[4][4];
#pragma unroll
    for (int r = 0; r < 4; ++r) {
      float4 da = *(const float4*)(S0 + (i0 + r) * 64 + j0);
      ab[r][0] = da.x + ((i0 + r) == (j0 + 0) ? 1.f : 0.f);
      ab[r][1] = da.y + ((i0 + r) == (j0 + 1) ? 1.f : 0.f);
      ab[r][2] = da.z + ((i0 + r) == (j0 + 2) ? 1.f : 0.f);
      ab[r][3] = da.w + ((i0 + r) == (j0 + 3) ? 1.f : 0.f);
    }

    // B_bar partials: bbp(i,q) = sum_k 1/(k+1)! * sum_{m in q-quarter} dA^k[i][l]*B[l]
    float Bv[16];
#pragma unroll
    for (int m = 0; m < 16; m += 4) {
      float4 b4 = *(const float4*)(B + bq * 16 + m);
      Bv[m] = b4.x; Bv[m + 1] = b4.y; Bv[m + 2] = b4.z; Bv[m + 3] = b4.w;
    }
    float bbp = (bq == (bi >> 4)) ? B[bi] : 0.f;  // k=0 term
    // k=1 term: dA row bi, cols [16q,16q+16), coef 1/2
#pragma unroll
    for (int m = 0; m < 16; m += 4) {
      float4 a4 = *(const float4*)(S0 + bi * 64 + bq * 16 + m);
      bbp += 0.5f * (a4.x * Bv[m] + a4.y * Bv[m + 1] + a4.z * Bv[m + 2] + a4.w * Bv[m + 3]);
    }

    // Taylor: P(k)T = mm(XT=dA, Y=P(k-1)T); P1T = dAT lives in S1; ping-pong S1<->S2
    float fact = 1.f;
    int ping = 1;
    for (int k = 2; k <= 8; ++k) {
      const float* Yp = Lh + 4096 * ping;
      float* Cp = Lh + 4096 * (3 - ping);
      float c[4][4] = {{0.f}};
      mm64_core(S0, Yp, i0, j0, c);
      store_tile(Cp, i0, j0, c);
      __syncthreads();
      fact *= (float)k;
      float ivf = 1.f / fact;              // 1/k!
      float ivf1 = ivf / (float)(k + 1);   // 1/(k+1)!
      // A_bar += Pk/k!  (Pk[i][j] = PkT[j][i])
#pragma unroll
      for (int s = 0; s < 4; ++s) {
        float4 pv = *(const float4*)(Cp + (j0 + s) * 64 + i0);
        ab[0][s] += pv.x * ivf; ab[1][s] += pv.y * ivf;
        ab[2][s] += pv.z * ivf; ab[3][s] += pv.w * ivf;
      }
      // B_bar partial
#pragma unroll
      for (int m = 0; m < 16; ++m)
        bbp += ivf1 * Cp[(bq * 16 + m) * 64 + bi] * Bv[m];
      ping = 3 - ping;
    }
    // combine bbp -> wave0 registers (B_bar).  pp scratch in S1 (P7T, dead).
    S1[bq * 64 + bi] = bbp;
    __syncthreads();
    float breg = 0.f;
    if (tid < 64)
      breg = dt * (S1[tid] + S1[64 + tid] + S1[128 + tid] + S1[192 + tid]);
    __syncthreads();
    // write AB -> S1, ABT -> S2 (S2 = P8T, dead)
    store_tile(S1, i0, j0, ab);
#pragma unroll
    for (int s = 0; s < 4; ++s)
      *(float4*)(S2 + (j0 + s) * 64 + i0) = make_float4(ab[0][s], ab[1][s], ab[2][s], ab[3][s]);
    __syncthreads();

    // U-chain (wave 0): U_j = C·A_bar^j, rows from ABT(S2), UT -> S3, ubuf in S0
    const int wv = tid >> 6, ln = tid & 63;
    if (wv == 0) chain64(S2, S0, S3, ln, C[ln]);
    __syncthreads();

    // Squarings to A64: rotation over S0,S1,S2 (mm + transpose-pass)
    int sM = 1, sT = 2, sF = 0;
    for (int sq = 0; sq < 6; ++sq) {
      float c[4][4] = {{0.f}};
      mm64_core(Lh + 4096 * sT, Lh + 4096 * sM, i0, j0, c);
      store_tile(Lh + 4096 * sF, i0, j0, c);
      __syncthreads();
      if (sq < 5) {
        const float* F = Lh + 4096 * sF;
        float* Dst = Lh + 4096 * sM;  // old M slot becomes MoutT
        float4 v0 = *(const float4*)(F + (i0 + 0) * 64 + j0);
        float4 v1 = *(const float4*)(F + (i0 + 1) * 64 + j0);
        float4 v2 = *(const float4*)(F + (i0 + 2) * 64 + j0);
        float4 v3 = *(const float4*)(F + (i0 + 3) * 64 + j0);
        *(float4*)(Dst + (j0 + 0) * 64 + i0) = make_float4(v0.x, v1.x, v2.x, v3.x);
        *(float4*)(Dst + (j0 + 1) * 64 + i0) = make_float4(v0.y, v1.y, v2.y, v3.y);
        *(float4*)(Dst + (j0 + 2) * 64 + i0) = make_float4(v0.z, v1.z, v2.z, v3.z);
        *(float4*)(Dst + (j0 + 3) * 64 + i0) = make_float4(v0.w, v1.w, v2.w, v3.w);
        __syncthreads();
        int nM = sF, nT = sM, nF = sT;
        sM = nM; sT = nT; sF = nF;
      }
    }
    // After sq5: A64 row-major in slot sF (no transpose needed).  Dead: sM, sT.
    const int a64s = sF, vslot = sM, ubslot = sT;
    __syncthreads();

    // V-chain (wave 0): V_m = A64^m·B_bar, Vmat[l][m] -> vslot
    if (wv == 0) chain64(Lh + 4096 * a64s, Lh + 4096 * ubslot, Lh + 4096 * vslot, ln, breg);
    __syncthreads();

    // H[j][m] = sum_l UT[l][j]*Vmat[l][m] = h[64m + j]  -> global
    {
      float c[4][4] = {{0.f}};
      mm64_core(S3, Lh + 4096 * vslot, i0, j0, c);
#pragma unroll
      for (int s = 0; s < 4; ++s)
        *(float4*)(h_ws + 64 * (j0 + s) + i0) = make_float4(c[0][s], c[1][s], c[2][s], c[3][s]);
    }
  } else {
    // ================= p[b,t] = u·W_in (1024 blocks, wave per row) =================
    const int pb = blockIdx.x - 1;
    const int ln = tid & 63;
    const int w = (pb << 2) | (tid >> 6);  // global wave id, 0..4095
    float4 w0 = *(const float4*)(Win + ln * 8);
    float4 w1 = *(const float4*)(Win + ln * 8 + 4);
    const size_t base = (size_t)w * 16 * 512 + (size_t)ln * 8;
#pragma unroll 2
    for (int i = 0; i < 16; ++i) {
      const float* up = u + base + (size_t)i * 512;
      float4 a0 = *(const float4*)up;
      float4 a1 = *(const float4*)(up + 4);
      float v = a0.x * w0.x + a0.y * w0.y + a0.z * w0.z + a0.w * w0.w +
                a1.x * w1.x + a1.y * w1.y + a1.z * w1.z + a1.w * w1.w;
#pragma unroll
      for (int off = 32; off > 0; off >>= 1) v += __shfl_xor(v, off);
      if (ln == 0) p_ws[w * 16 + i] = v;
    }
  }
}

extern "C" __global__ __launch_bounds__(256) void s4_k2(
    const float* __restrict__ p_ws, const float* __restrict__ h_ws,
    const float* __restrict__ Dp, const float* __restrict__ Wout,
    float* __restrict__ out) {
  __shared__ __align__(16) float hpad[4352];  // [0..255]=0 pad, [256+k]=h[k]
  __shared__ __align__(16) float ps[4096];    // p[b, 0..4095]
  __shared__ __align__(16) float sv[256];
  __shared__ __align__(16) float wo[512];
  const int tid = threadIdx.x;
  const int b = blockIdx.x >> 4, tile = blockIdx.x & 15;

  hpad[tid] = 0.f;
#pragma unroll
  for (int i = 0; i < 4; ++i) {
    int idx = i * 1024 + tid * 4;
    *(float4*)(hpad + 256 + idx) = *(const float4*)(h_ws + idx);
    *(float4*)(ps + idx) = *(const float4*)(p_ws + (b << 12) + idx);
  }
  if (tid < 128) *(float4*)(wo + tid * 4) = *(const float4*)(Wout + tid * 4);
  __syncthreads();

  const int t0 = tile << 8;
  float acc = Dp[0] * ps[t0 + tid];
  const int hoff = 256 + t0 + tid - 1;
  for (int c = 0; c <= tile; ++c) {
    const float* pc = ps + (c << 8);
    const int ho = hoff - (c << 8);
#pragma unroll 4
    for (int j = 0; j < 64; ++j) {
      float4 p4 = *(const float4*)(pc + 4 * j);
      acc += p4.x * hpad[ho - 4 * j]     + p4.y * hpad[ho - 4 * j - 1] +
             p4.z * hpad[ho - 4 * j - 2] + p4.w * hpad[ho - 4 * j - 3];
    }
  }
  sv[tid] = acc;
  __syncthreads();

  // epilogue: out[b, t0+r, :] = sv[r] * W_out[:], coalesced float4 stores
  const int ln = tid & 63, wv = tid >> 6;
  float4 wa = *(const float4*)(wo + ln * 8);
  float4 wb = *(const float4*)(wo + ln * 8 + 4);
  const size_t rowbase = ((size_t)(b << 12) + (size_t)t0) * 512 + (size_t)ln * 8;
  for (int r = wv; r < 256; r += 4) {
    float s = sv[r];
    float* op = out + rowbase + (size_t)r * 512;
    *(float4*)op = make_float4(s * wa.x, s * wa.y, s * wa.z, s * wa.w);
    *(float4*)(op + 4) = make_float4(s * wb.x, s * wb.y, s * wb.z, s * wb.w);
  }
}

extern "C" void kernel_launch(void* const* d_in, const int* in_sizes, int n_in,
                              void* d_out, int out_size, void* d_ws, size_t ws_size,
                              hipStream_t stream) {
  const float* u = (const float*)d_in[0];
  const float* A = (const float*)d_in[1];
  const float* B = (const float*)d_in[2];
  const float* C = (const float*)d_in[3];
  const float* D = (const float*)d_in[4];
  const float* logdt = (const float*)d_in[5];
  const float* Win = (const float*)d_in[6];
  const float* Wout = (const float*)d_in[7];
  float* outp = (float*)d_out;
  float* p_ws = (float*)d_ws;        // 65536 floats
  float* h_ws = p_ws + 65536;        // 4096 floats

  s4_k1<<<1025, 256, 0, stream>>>(u, A, B, C, logdt, Win, p_ws, h_ws);
  s4_k2<<<256, 256, 0, stream>>>(p_ws, h_ws, D, Wout, outp);
}

// Round 2
// 340.453 us; speedup vs baseline: 1.5012x; 1.5012x over previous
//
#include <hip/hip_runtime.h>
#include <math.h>

// S4 forward:
//   p[b,t] = u[b,t,:]·W_in          (K1, blocks 1..1024)
//   h[k]   = C·A_bar^k·B_bar        (K1, block 0: Taylor + squarings + U-doubling + V-chain)
//   s[b,t] = D·p[b,t] + sum_{k<t} h[k]·p[b,t-1-k]   (K2 conv, chunk-parallel waves)
//   out[b,t,d] = s[b,t]·W_out[d]    (K2 epilogue, coalesced stream)

#define S0 (Lh)
#define S1 (Lh + 4096)
#define S2 (Lh + 8192)
#define S3 (Lh + 12288)

// C[i0+r][j0+s] += sum_l XT[l][i0+r] * Y[l][j0+s]   (i.e. C = X·Y given X^T)
__device__ __forceinline__ void mm64_core(const float* XT, const float* Y,
                                          int i0, int j0, float c[4][4]) {
#pragma unroll 4
  for (int l = 0; l < 64; ++l) {
    float4 xv = *(const float4*)(XT + l * 64 + i0);
    float4 yv = *(const float4*)(Y + l * 64 + j0);
    c[0][0] += xv.x * yv.x; c[0][1] += xv.x * yv.y; c[0][2] += xv.x * yv.z; c[0][3] += xv.x * yv.w;
    c[1][0] += xv.y * yv.x; c[1][1] += xv.y * yv.y; c[1][2] += xv.y * yv.z; c[1][3] += xv.y * yv.w;
    c[2][0] += xv.z * yv.x; c[2][1] += xv.z * yv.y; c[2][2] += xv.z * yv.z; c[2][3] += xv.z * yv.w;
    c[3][0] += xv.w * yv.x; c[3][1] += xv.w * yv.y; c[3][2] += xv.w * yv.z; c[3][3] += xv.w * yv.w;
  }
}

__device__ __forceinline__ void store_tile(float* Cp, int i0, int j0, float c[4][4]) {
#pragma unroll
  for (int r = 0; r < 4; ++r)
    *(float4*)(Cp + (i0 + r) * 64 + j0) = make_float4(c[r][0], c[r][1], c[r][2], c[r][3]);
}

// 63-step matvec chain (single wave, wave-synchronous LDS round-trip, NO volatile):
// v_{j+1}[ln] = dot(rowsrc row ln, v_j); outT[ln][j] = v_j[ln].
__device__ __forceinline__ void chain64(const float* rowsrc, float* ubuf,
                                        float* outT, int ln, float v0) {
  float row[64];
#pragma unroll
  for (int q = 0; q < 16; ++q) {
    float4 rv = *(const float4*)(rowsrc + ln * 64 + 4 * q);
    row[4 * q] = rv.x; row[4 * q + 1] = rv.y; row[4 * q + 2] = rv.z; row[4 * q + 3] = rv.w;
  }
  float v = v0;
  for (int jq = 0; jq < 16; ++jq) {
    float q0 = v, q1, q2, q3;
#pragma unroll
    for (int m = 1; m < 4; ++m) {
      ubuf[ln] = v;
      __builtin_amdgcn_wave_barrier();
      float a0 = 0.f, a1 = 0.f, a2 = 0.f, a3 = 0.f;
#pragma unroll
      for (int q = 0; q < 16; ++q) {
        float4 uv = *(const float4*)(ubuf + 4 * q);
        a0 += row[4 * q] * uv.x; a1 += row[4 * q + 1] * uv.y;
        a2 += row[4 * q + 2] * uv.z; a3 += row[4 * q + 3] * uv.w;
      }
      __builtin_amdgcn_wave_barrier();
      v = (a0 + a1) + (a2 + a3);
      if (m == 1) q1 = v; else if (m == 2) q2 = v; else q3 = v;
    }
    *(float4*)(outT + ln * 64 + 4 * jq) = make_float4(q0, q1, q2, q3);
    if (jq < 15) {
      ubuf[ln] = v;
      __builtin_amdgcn_wave_barrier();
      float a0 = 0.f, a1 = 0.f, a2 = 0.f, a3 = 0.f;
#pragma unroll
      for (int q = 0; q < 16; ++q) {
        float4 uv = *(const float4*)(ubuf + 4 * q);
        a0 += row[4 * q] * uv.x; a1 += row[4 * q + 1] * uv.y;
        a2 += row[4 * q + 2] * uv.z; a3 += row[4 * q + 3] * uv.w;
      }
      __builtin_amdgcn_wave_barrier();
      v = (a0 + a1) + (a2 + a3);
    }
  }
}

extern "C" __global__ __launch_bounds__(256) void s4_k1(
    const float* __restrict__ u, const float* __restrict__ A, const float* __restrict__ B,
    const float* __restrict__ C, const float* __restrict__ logdt, const float* __restrict__ Win,
    float* __restrict__ p_ws, float* __restrict__ h_ws) {
  __shared__ __align__(16) float Lh[16384];  // 4 slots of 64x64 f32
  __shared__ __align__(16) float cbuf[64];   // chain round-trip buffer
  const int tid = threadIdx.x;

  if (blockIdx.x == 0) {
    // ================= h[k] pipeline (one block) =================
    float dt = expf(logdt[0]);
    dt = fminf(fmaxf(dt, 0.001f), 0.1f);

    // load dA = dt*A into S0 (row-major) and dAT into S1
#pragma unroll
    for (int n = 0; n < 16; ++n) {
      int e = tid * 16 + n;
      int i = e >> 6, j = e & 63;
      float v = A[e] * dt;
      S0[e] = v;
      S1[j * 64 + i] = v;
    }
    __syncthreads();

    const int i0 = (tid & 15) << 2, j0 = (tid >> 4) << 2;
    const int bi = tid & 63, bq = tid >> 6;
    const int wv = tid >> 6, ln = tid & 63;

    // A_bar tile accumulator: I + dA + sum_{k=2..5} dA^k/k!
    float ab[4][4];
#pragma unroll
    for (int r = 0; r < 4; ++r) {
      float4 da = *(const float4*)(S0 + (i0 + r) * 64 + j0);
      ab[r][0] = da.x + ((i0 + r) == (j0 + 0) ? 1.f : 0.f);
      ab[r][1] = da.y + ((i0 + r) == (j0 + 1) ? 1.f : 0.f);
      ab[r][2] = da.z + ((i0 + r) == (j0 + 2) ? 1.f : 0.f);
      ab[r][3] = da.w + ((i0 + r) == (j0 + 3) ? 1.f : 0.f);
    }

    // B_bar partials: bbp(i,q) = sum_k 1/(k+1)! * sum_{m in q-quarter} dA^k[i][l]*B[l]
    float Bv[16];
#pragma unroll
    for (int m = 0; m < 16; m += 4) {
      float4 b4 = *(const float4*)(B + bq * 16 + m);
      Bv[m] = b4.x; Bv[m + 1] = b4.y; Bv[m + 2] = b4.z; Bv[m + 3] = b4.w;
    }
    float bbp = (bq == (bi >> 4)) ? B[bi] : 0.f;  // k=0 term
#pragma unroll
    for (int m = 0; m < 16; m += 4) {
      float4 a4 = *(const float4*)(S0 + bi * 64 + bq * 16 + m);
      bbp += 0.5f * (a4.x * Bv[m] + a4.y * Bv[m + 1] + a4.z * Bv[m + 2] + a4.w * Bv[m + 3]);
    }

    // Taylor K=5 (||dA|| ~ 0.035 -> truncation ~3e-12): ping-pong S1<->S2
    float fact = 1.f;
    int ping = 1;
    for (int k = 2; k <= 5; ++k) {
      const float* Yp = Lh + 4096 * ping;
      float* Cp = Lh + 4096 * (3 - ping);
      float c[4][4] = {{0.f}};
      mm64_core(S0, Yp, i0, j0, c);
      store_tile(Cp, i0, j0, c);
      __syncthreads();
      fact *= (float)k;
      float ivf = 1.f / fact;
      float ivf1 = ivf / (float)(k + 1);
#pragma unroll
      for (int s = 0; s < 4; ++s) {
        float4 pv = *(const float4*)(Cp + (j0 + s) * 64 + i0);
        ab[0][s] += pv.x * ivf; ab[1][s] += pv.y * ivf;
        ab[2][s] += pv.z * ivf; ab[3][s] += pv.w * ivf;
      }
#pragma unroll
      for (int m = 0; m < 16; ++m)
        bbp += ivf1 * Cp[(bq * 16 + m) * 64 + bi] * Bv[m];
      ping = 3 - ping;
    }
    // combine bbp -> wave0 registers (B_bar)
    __syncthreads();
    S1[bq * 64 + bi] = bbp;
    __syncthreads();
    float breg = 0.f;
    if (tid < 64)
      breg = dt * (S1[tid] + S1[64 + tid] + S1[128 + tid] + S1[192 + tid]);
    __syncthreads();
    // AB -> S1, ABT -> S2
    store_tile(S1, i0, j0, ab);
#pragma unroll
    for (int s = 0; s < 4; ++s)
      *(float4*)(S2 + (j0 + s) * 64 + i0) = make_float4(ab[0][s], ab[1][s], ab[2][s], ab[3][s]);
    __syncthreads();

    // Seed UT cols 0..3 (wave 0): U_0=C, U_{j+1} = U_j·AB via ABT rows
    if (wv == 0) {
      float uq0, uq1, uq2, uq3;
      float uv = C[ln];
      uq0 = uv;
#pragma unroll
      for (int stp = 1; stp < 4; ++stp) {
        cbuf[ln] = uv;
        __builtin_amdgcn_wave_barrier();
        float a0 = 0.f, a1 = 0.f, a2 = 0.f, a3 = 0.f;
#pragma unroll
        for (int q = 0; q < 16; ++q) {
          float4 rv = *(const float4*)(S2 + ln * 64 + 4 * q);
          float4 xv = *(const float4*)(cbuf + 4 * q);
          a0 += rv.x * xv.x; a1 += rv.y * xv.y; a2 += rv.z * xv.z; a3 += rv.w * xv.w;
        }
        __builtin_amdgcn_wave_barrier();
        uv = (a0 + a1) + (a2 + a3);
        if (stp == 1) uq1 = uv; else if (stp == 2) uq2 = uv; else uq3 = uv;
      }
      *(float4*)(S3 + ln * 64) = make_float4(uq0, uq1, uq2, uq3);
    }
    __syncthreads();

    // Squarings AB -> A64, with U-doubling folded in:
    // after sq s (result M_{2^{s+1}}), rows [R,2R) of U = U[0,R)·M_R for R=4<<(s-1)
    int sM = 1, sT = 2, sF = 0;
    for (int sq = 0; sq < 6; ++sq) {
      {
        float c[4][4] = {{0.f}};
        mm64_core(Lh + 4096 * sT, Lh + 4096 * sM, i0, j0, c);
        store_tile(Lh + 4096 * sF, i0, j0, c);
      }
      __syncthreads();
      if (sq >= 1 && sq <= 4) {
        const int R = 4 << (sq - 1);
        if (i0 < R) {
          float c2[4][4] = {{0.f}};
          mm64_core(S3, Lh + 4096 * sF, i0, j0, c2);
#pragma unroll
          for (int s = 0; s < 4; ++s)
            *(float4*)(S3 + (j0 + s) * 64 + R + i0) =
                make_float4(c2[0][s], c2[1][s], c2[2][s], c2[3][s]);
        }
      }
      if (sq < 5) {
        const float* F = Lh + 4096 * sF;
        float* Dst = Lh + 4096 * sM;
        float4 v0 = *(const float4*)(F + (i0 + 0) * 64 + j0);
        float4 v1 = *(const float4*)(F + (i0 + 1) * 64 + j0);
        float4 v2 = *(const float4*)(F + (i0 + 2) * 64 + j0);
        float4 v3 = *(const float4*)(F + (i0 + 3) * 64 + j0);
        *(float4*)(Dst + (j0 + 0) * 64 + i0) = make_float4(v0.x, v1.x, v2.x, v3.x);
        *(float4*)(Dst + (j0 + 1) * 64 + i0) = make_float4(v0.y, v1.y, v2.y, v3.y);
        *(float4*)(Dst + (j0 + 2) * 64 + i0) = make_float4(v0.z, v1.z, v2.z, v3.z);
        *(float4*)(Dst + (j0 + 3) * 64 + i0) = make_float4(v0.w, v1.w, v2.w, v3.w);
        __syncthreads();
        int nM = sF, nT = sM, nF = sT;
        sM = nM; sT = nT; sF = nF;
      }
    }
    // A64 row-major in S1.  Dead: S0, S2.  UT alive in S3.
    // V-chain (wave 0): V[l][m] = (A64^m·B_bar)[l] -> S0
    if (wv == 0) chain64(S1, cbuf, S0, ln, breg);
    __syncthreads();

    // H[j][m] = sum_l UT[l][j]*V[l][m] = h[64m + j]  -> global
    {
      float c[4][4] = {{0.f}};
      mm64_core(S3, S0, i0, j0, c);
#pragma unroll
      for (int s = 0; s < 4; ++s)
        *(float4*)(h_ws + 64 * (j0 + s) + i0) = make_float4(c[0][s], c[1][s], c[2][s], c[3][s]);
    }
  } else {
    // ================= p[b,t] = u·W_in (1024 blocks, wave per row) =================
    const int pb = blockIdx.x - 1;
    const int ln = tid & 63;
    const int w = (pb << 2) | (tid >> 6);  // global wave id, 0..4095
    float4 w0 = *(const float4*)(Win + ln * 8);
    float4 w1 = *(const float4*)(Win + ln * 8 + 4);
    const size_t base = (size_t)w * 16 * 512 + (size_t)ln * 8;
#pragma unroll 8
    for (int i = 0; i < 16; ++i) {
      const float* up = u + base + (size_t)i * 512;
      float4 a0 = *(const float4*)up;
      float4 a1 = *(const float4*)(up + 4);
      float v = a0.x * w0.x + a0.y * w0.y + a0.z * w0.z + a0.w * w0.w +
                a1.x * w1.x + a1.y * w1.y + a1.z * w1.z + a1.w * w1.w;
#pragma unroll
      for (int off = 32; off > 0; off >>= 1) v += __shfl_xor(v, off);
      if (ln == 0) p_ws[w * 16 + i] = v;
    }
  }
}

extern "C" __global__ __launch_bounds__(256) void s4_k2(
    const float* __restrict__ p_ws, const float* __restrict__ h_ws,
    const float* __restrict__ Dp, const float* __restrict__ Wout,
    float* __restrict__ out) {
  __shared__ __align__(16) float hpad[4352];  // [0..255]=0 pad, [256+k]=h[k]
  __shared__ __align__(16) float ps[4096];    // p[b, 0..4095]
  __shared__ __align__(16) float part[1024];  // per-wave partial s
  __shared__ __align__(16) float sv[256];
  __shared__ __align__(16) float wo[512];
  const int tid = threadIdx.x;
  const int b = blockIdx.x >> 4, tile = blockIdx.x & 15;

  hpad[tid] = 0.f;
#pragma unroll
  for (int i = 0; i < 4; ++i) {
    int idx = i * 1024 + tid * 4;
    *(float4*)(hpad + 256 + idx) = *(const float4*)(h_ws + idx);
    *(float4*)(ps + idx) = *(const float4*)(p_ws + (b << 12) + idx);
  }
  if (tid < 128) *(float4*)(wo + tid * 4) = *(const float4*)(Wout + tid * 4);
  __syncthreads();

  // conv: lane owns outputs t = t0 + 4*ln + {0..3}; waves partition chunks c.
  const int wv = tid >> 6, ln = tid & 63;
  const int t0 = tile << 8;
  float a0 = 0.f, a1 = 0.f, a2 = 0.f, a3 = 0.f;
  for (int c = wv; c <= tile; c += 4) {
    // W(k) = t0 + 4*ln - 1 - 256c - k; hA = h[W-3..W], hB = h[W+1..W+4], 16B-aligned
    const float* pA = hpad + 256 + t0 + 4 * ln - 4 - (c << 8);
    const float* pc = ps + (c << 8);
#pragma unroll 4
    for (int k = 0; k < 256; k += 4) {
      float4 p4 = *(const float4*)(pc + k);      // broadcast
      float4 hA = *(const float4*)(pA - k);
      float4 hB = *(const float4*)(pA - k + 4);
      a0 += p4.x * hA.w + p4.y * hA.z + p4.z * hA.y + p4.w * hA.x;
      a1 += p4.x * hB.x + p4.y * hA.w + p4.z * hA.z + p4.w * hA.y;
      a2 += p4.x * hB.y + p4.y * hB.x + p4.z * hA.w + p4.w * hA.z;
      a3 += p4.x * hB.z + p4.y * hB.y + p4.z * hB.x + p4.w * hA.w;
    }
  }
  *(float4*)(part + (wv << 8) + (ln << 2)) = make_float4(a0, a1, a2, a3);
  __syncthreads();
  sv[tid] = Dp[0] * ps[t0 + tid] + part[tid] + part[256 + tid] + part[512 + tid] + part[768 + tid];
  __syncthreads();

  // epilogue: out[b, t0+r, :] = sv[r] * W_out[:], coalesced float4 stores
  float4 wa = *(const float4*)(wo + ln * 8);
  float4 wb = *(const float4*)(wo + ln * 8 + 4);
  const size_t rowbase = ((size_t)(b << 12) + (size_t)t0) * 512 + (size_t)ln * 8;
  for (int r = wv; r < 256; r += 4) {
    float s = sv[r];
    float* op = out + rowbase + (size_t)r * 512;
    *(float4*)op = make_float4(s * wa.x, s * wa.y, s * wa.z, s * wa.w);
    *(float4*)(op + 4) = make_float4(s * wb.x, s * wb.y, s * wb.z, s * wb.w);
  }
}

extern "C" void kernel_launch(void* const* d_in, const int* in_sizes, int n_in,
                              void* d_out, int out_size, void* d_ws, size_t ws_size,
                              hipStream_t stream) {
  const float* u = (const float*)d_in[0];
  const float* A = (const float*)d_in[1];
  const float* B = (const float*)d_in[2];
  const float* C = (const float*)d_in[3];
  const float* D = (const float*)d_in[4];
  const float* logdt = (const float*)d_in[5];
  const float* Win = (const float*)d_in[6];
  const float* Wout = (const float*)d_in[7];
  float* outp = (float*)d_out;
  float* p_ws = (float*)d_ws;        // 65536 floats
  float* h_ws = p_ws + 65536;        // 4096 floats

  s4_k1<<<1025, 256, 0, stream>>>(u, A, B, C, logdt, Win, p_ws, h_ws);
  s4_k2<<<256, 256, 0, stream>>>(p_ws, h_ws, D, Wout, outp);
}